// Round 1
// baseline (951.043 us; speedup 1.0000x reference)
//
#include <hip/hip_runtime.h>
#include <cstdint>
#include <cstddef>

#define VCUBE 35937      // 33^3
#define LUT_CH 107811    // 3*33^3

// ---------------- resize bilinear 2048x2048 -> 256x256 ----------------
__global__ __launch_bounds__(256) void resize_kernel(const float* __restrict__ in,
                                                     float* __restrict__ out) {
    int idx = blockIdx.x * 256 + threadIdx.x;   // (bc, oy, ox), bc = b*3+c
    int ox = idx & 255;
    int oy = (idx >> 8) & 255;
    int bc = idx >> 16;
    float sy = (oy + 0.5f) * 8.0f - 0.5f;
    float sx = (ox + 0.5f) * 8.0f - 0.5f;
    int y0 = (int)floorf(sy);
    int x0 = (int)floorf(sx);
    float fy = sy - (float)y0;
    float fx = sx - (float)x0;
    const float* p  = in + (size_t)bc * 2048 * 2048;
    const float* r0 = p + (size_t)y0 * 2048;
    const float* r1 = r0 + 2048;
    float a = r0[x0], b = r0[x0 + 1], c = r1[x0], d = r1[x0 + 1];
    float top = a + fx * (b - a);
    float bot = c + fx * (d - c);
    out[idx] = top + fy * (bot - top);
}

// ---------------- conv 3x3 stride2 pad1 + leaky relu ----------------
__global__ __launch_bounds__(256) void conv_s2_lrelu(const float* __restrict__ in,
                                                     const float* __restrict__ w,
                                                     const float* __restrict__ bias,
                                                     float* __restrict__ out,
                                                     int B, int CI, int CO, int IH, int IW) {
    int OH = IH >> 1, OW = IW >> 1;
    int total = B * CO * OH * OW;
    int idx = blockIdx.x * 256 + threadIdx.x;
    if (idx >= total) return;
    int ow = idx % OW;
    int t = idx / OW;
    int oh = t % OH; t /= OH;
    int co = t % CO;
    int b  = t / CO;
    float acc = bias[co];
    const float* wp = w + (size_t)co * CI * 9;
    const float* ip = in + (size_t)b * CI * IH * IW;
    int ih0 = oh * 2 - 1, iw0 = ow * 2 - 1;
    for (int ci = 0; ci < CI; ci++) {
        const float* ipc = ip + (size_t)ci * IH * IW;
        const float* wpc = wp + ci * 9;
#pragma unroll
        for (int kh = 0; kh < 3; kh++) {
            int ih = ih0 + kh;
            if (ih < 0 || ih >= IH) continue;
            const float* row = ipc + (size_t)ih * IW;
#pragma unroll
            for (int kw = 0; kw < 3; kw++) {
                int iw = iw0 + kw;
                if (iw < 0 || iw >= IW) continue;
                acc = fmaf(row[iw], wpc[kh * 3 + kw], acc);
            }
        }
    }
    out[idx] = acc >= 0.f ? acc : 0.2f * acc;
}

// ---------------- instance norm, in place, one block per (b,c) plane ----------------
__global__ __launch_bounds__(256) void inorm_kernel(float* __restrict__ x,
                                                    const float* __restrict__ g,
                                                    const float* __restrict__ be,
                                                    int C, int HW) {
    int plane = blockIdx.x;       // b*C + c
    int c = plane % C;
    float* p = x + (size_t)plane * HW;
    int t = threadIdx.x;
    float s = 0.f, s2 = 0.f;
    for (int i = t; i < HW; i += 256) {
        float v = p[i];
        s += v;
        s2 = fmaf(v, v, s2);
    }
    __shared__ float ss[256], sq[256];
    ss[t] = s; sq[t] = s2;
    __syncthreads();
    for (int off = 128; off > 0; off >>= 1) {
        if (t < off) { ss[t] += ss[t + off]; sq[t] += sq[t + off]; }
        __syncthreads();
    }
    __shared__ float sc, sh;
    if (t == 0) {
        float inv_n = 1.0f / (float)HW;
        float mean = ss[0] * inv_n;
        float var  = sq[0] * inv_n - mean * mean;
        float scale = g[c] / sqrtf(var + 1e-5f);
        sc = scale;
        sh = be[c] - mean * scale;
    }
    __syncthreads();
    for (int i = t; i < HW; i += 256) p[i] = fmaf(p[i], sc, sh);
}

// ---------------- 4x4 avg pool (b,128,8,8) -> (b,512) ----------------
__global__ __launch_bounds__(256) void pool_kernel(const float* __restrict__ x5,
                                                   float* __restrict__ xvec, int n) {
    int idx = blockIdx.x * 256 + threadIdx.x;   // b*512 + (c*4 + h2*2 + w2)
    if (idx >= n) return;
    int o = idx & 511;
    int b = idx >> 9;
    int c  = o >> 2;
    int h2 = (o >> 1) & 1;
    int w2 = o & 1;
    const float* p = x5 + ((size_t)(b * 128 + c)) * 64 + h2 * 32 + w2 * 4;
    float s = 0.f;
#pragma unroll
    for (int h = 0; h < 4; h++)
#pragma unroll
        for (int ww = 0; ww < 4; ww++) s += p[h * 8 + ww];
    xvec[idx] = s * (1.0f / 16.0f);
}

// ---------------- head: gemvs + softmax + cumsum -> weights, vertices ----------------
__global__ __launch_bounds__(128) void head_kernel(const float* __restrict__ xvec,
                                                   const float* __restrict__ wgen_w,
                                                   const float* __restrict__ wgen_b,
                                                   const float* __restrict__ ada_w,
                                                   const float* __restrict__ ada_b,
                                                   float* __restrict__ gweights,
                                                   float* __restrict__ vertices) {
    int b = blockIdx.x;
    int t = threadIdx.x;   // 128 threads
    __shared__ float xv[512];
    __shared__ float logits[96];
    for (int i = t; i < 512; i += 128) xv[i] = xvec[b * 512 + i];
    __syncthreads();
    if (t < 96) {
        float s = ada_b[t];
        for (int k = 0; k < 512; k++) s = fmaf(xv[k], ada_w[k * 96 + t], s);
        logits[t] = s;
    } else if (t < 99) {
        int j = t - 96;
        float s = wgen_b[j];
        for (int k = 0; k < 512; k++) s = fmaf(xv[k], wgen_w[k * 3 + j], s);
        gweights[b * 3 + j] = s;
    }
    __syncthreads();
    if (t < 3) {
        const float* l = logits + t * 32;
        float m = l[0];
#pragma unroll
        for (int i = 1; i < 32; i++) m = fmaxf(m, l[i]);
        float e[32];
        float sum = 0.f;
#pragma unroll
        for (int i = 0; i < 32; i++) { e[i] = expf(l[i] - m); sum += e[i]; }
        float inv = 1.0f / sum;
        float* vp = vertices + b * 99 + t * 33;
        vp[0] = 0.f;
        float cum = 0.f;
#pragma unroll
        for (int i = 0; i < 32; i++) { cum = fmaf(e[i], inv, cum); vp[i + 1] = cum; }
    }
}

// ---------------- luts = weights (b,3) @ basis_w (3, 3*V^3) ----------------
__global__ __launch_bounds__(256) void luts_kernel(const float* __restrict__ basis_w,
                                                   const float* __restrict__ gweights,
                                                   float* __restrict__ luts, int B) {
    int j = blockIdx.x * 256 + threadIdx.x;
    if (j >= LUT_CH) return;
    float b0 = basis_w[j];
    float b1 = basis_w[LUT_CH + j];
    float b2 = basis_w[2 * LUT_CH + j];
    for (int b = 0; b < B; b++) {
        luts[(size_t)b * LUT_CH + j] =
            gweights[b * 3 + 0] * b0 + gweights[b * 3 + 1] * b1 + gweights[b * 3 + 2] * b2;
    }
}

// ---------------- final AiLUT trilinear transform ----------------
__device__ __forceinline__ void lut_px(float r, float g, float bl,
                                       const float* __restrict__ lut,
                                       const float* sv,
                                       float* o0, float* o1, float* o2) {
    float q[3];
    q[0] = fminf(fmaxf(r, 0.f), 1.f);
    q[1] = fminf(fmaxf(g, 0.f), 1.f);
    q[2] = fminf(fmaxf(bl, 0.f), 1.f);
    int   idx[3];
    float fr[3];
#pragma unroll
    for (int c = 0; c < 3; c++) {
        const float* v = sv + c * 33;
        float qc = q[c];
        // searchsorted right: count of v <= qc, over 33 sorted elements
        int lo = 0, hi = 33;
#pragma unroll
        for (int it = 0; it < 6; it++) {
            if (lo < hi) {
                int mid = (lo + hi) >> 1;
                if (v[mid] <= qc) lo = mid + 1; else hi = mid;
            }
        }
        int i0 = lo - 1;          // >=0 since v[0]==0 <= qc
        if (i0 > 31) i0 = 31;
        float v0 = v[i0], v1 = v[i0 + 1];
        float f = (qc - v0) / fmaxf(v1 - v0, 1e-10f);
        fr[c]  = fminf(fmaxf(f, 0.f), 1.f);
        idx[c] = i0;
    }
    int base = (idx[2] * 33 + idx[1]) * 33 + idx[0];
    float fR = fr[0], fG = fr[1], fB = fr[2];
    float res[3];
#pragma unroll
    for (int cc = 0; cc < 3; cc++) {
        const float* L = lut + cc * VCUBE + base;
        float c000 = L[0],    c001 = L[1];
        float c010 = L[33],   c011 = L[34];
        float c100 = L[1089], c101 = L[1090];
        float c110 = L[1122], c111 = L[1123];
        float c00 = c000 + fR * (c001 - c000);
        float c01 = c010 + fR * (c011 - c010);
        float c10 = c100 + fR * (c101 - c100);
        float c11 = c110 + fR * (c111 - c110);
        float c0 = c00 + fG * (c01 - c00);
        float c1 = c10 + fG * (c11 - c10);
        res[cc] = c0 + fB * (c1 - c0);
    }
    *o0 = res[0]; *o1 = res[1]; *o2 = res[2];
}

__global__ __launch_bounds__(256) void transform_kernel(const float* __restrict__ imgs,
                                                        const float* __restrict__ luts,
                                                        const float* __restrict__ vertices,
                                                        float* __restrict__ out) {
    const int N = 2048 * 2048;
    __shared__ float sv[99];
    int b = blockIdx.y;
    if (threadIdx.x < 99) sv[threadIdx.x] = vertices[b * 99 + threadIdx.x];
    __syncthreads();
    size_t pix = ((size_t)blockIdx.x * 256 + threadIdx.x) * 4;
    const float* ip = imgs + (size_t)b * 3 * N;
    float* op = out + (size_t)b * 3 * N;
    const float* lut = luts + (size_t)b * LUT_CH;
    float4 r  = *(const float4*)(ip + pix);
    float4 g  = *(const float4*)(ip + (size_t)N + pix);
    float4 bb = *(const float4*)(ip + (size_t)2 * N + pix);
    float4 o0, o1, o2;
    lut_px(r.x, g.x, bb.x, lut, sv, &o0.x, &o1.x, &o2.x);
    lut_px(r.y, g.y, bb.y, lut, sv, &o0.y, &o1.y, &o2.y);
    lut_px(r.z, g.z, bb.z, lut, sv, &o0.z, &o1.z, &o2.z);
    lut_px(r.w, g.w, bb.w, lut, sv, &o0.w, &o1.w, &o2.w);
    *(float4*)(op + pix) = o0;
    *(float4*)(op + (size_t)N + pix) = o1;
    *(float4*)(op + (size_t)2 * N + pix) = o2;
}

// ---------------- launch ----------------
extern "C" void kernel_launch(void* const* d_in, const int* in_sizes, int n_in,
                              void* d_out, int out_size, void* d_ws, size_t ws_size,
                              hipStream_t stream) {
    const float* imgs   = (const float*)d_in[0];
    const float* w1 = (const float*)d_in[1];  const float* b1 = (const float*)d_in[2];
    const float* g1 = (const float*)d_in[3];  const float* be1 = (const float*)d_in[4];
    const float* w2 = (const float*)d_in[5];  const float* b2 = (const float*)d_in[6];
    const float* g2 = (const float*)d_in[7];  const float* be2 = (const float*)d_in[8];
    const float* w3 = (const float*)d_in[9];  const float* b3 = (const float*)d_in[10];
    const float* g3 = (const float*)d_in[11]; const float* be3 = (const float*)d_in[12];
    const float* w4 = (const float*)d_in[13]; const float* b4 = (const float*)d_in[14];
    const float* g4 = (const float*)d_in[15]; const float* be4 = (const float*)d_in[16];
    const float* w5 = (const float*)d_in[17]; const float* b5 = (const float*)d_in[18];
    const float* wgen_w  = (const float*)d_in[19];
    const float* wgen_b  = (const float*)d_in[20];
    const float* basis_w = (const float*)d_in[21];
    const float* ada_w   = (const float*)d_in[22];
    const float* ada_b   = (const float*)d_in[23];
    float* out = (float*)d_out;

    const int B = in_sizes[0] / (3 * 2048 * 2048);

    float* ws = (float*)d_ws;
    size_t off = 0;
    float* x0 = ws + off;     off += (size_t)B * 3 * 256 * 256;
    float* x1 = ws + off;     off += (size_t)B * 16 * 128 * 128;
    float* x2 = ws + off;     off += (size_t)B * 32 * 64 * 64;
    float* x3 = ws + off;     off += (size_t)B * 64 * 32 * 32;
    float* x4 = ws + off;     off += (size_t)B * 128 * 16 * 16;
    float* x5 = ws + off;     off += (size_t)B * 128 * 8 * 8;
    float* xvec = ws + off;   off += (size_t)B * 512;
    float* gw = ws + off;     off += (size_t)((B * 3 + 7) / 8) * 8;
    float* vert = ws + off;   off += (size_t)((B * 99 + 7) / 8) * 8;
    float* luts = ws + off;   off += (size_t)B * LUT_CH;

    // 1. resize
    resize_kernel<<<(B * 3 * 256 * 256) / 256, 256, 0, stream>>>(imgs, x0);
    // 2. conv stack
    conv_s2_lrelu<<<(B * 16 * 128 * 128 + 255) / 256, 256, 0, stream>>>(x0, w1, b1, x1, B, 3, 16, 256, 256);
    inorm_kernel<<<B * 16, 256, 0, stream>>>(x1, g1, be1, 16, 128 * 128);
    conv_s2_lrelu<<<(B * 32 * 64 * 64 + 255) / 256, 256, 0, stream>>>(x1, w2, b2, x2, B, 16, 32, 128, 128);
    inorm_kernel<<<B * 32, 256, 0, stream>>>(x2, g2, be2, 32, 64 * 64);
    conv_s2_lrelu<<<(B * 64 * 32 * 32 + 255) / 256, 256, 0, stream>>>(x2, w3, b3, x3, B, 32, 64, 64, 64);
    inorm_kernel<<<B * 64, 256, 0, stream>>>(x3, g3, be3, 64, 32 * 32);
    conv_s2_lrelu<<<(B * 128 * 16 * 16 + 255) / 256, 256, 0, stream>>>(x3, w4, b4, x4, B, 64, 128, 32, 32);
    inorm_kernel<<<B * 128, 256, 0, stream>>>(x4, g4, be4, 128, 16 * 16);
    conv_s2_lrelu<<<(B * 128 * 8 * 8 + 255) / 256, 256, 0, stream>>>(x4, w5, b5, x5, B, 128, 128, 16, 16);
    // 3. pool -> xvec
    pool_kernel<<<(B * 512 + 255) / 256, 256, 0, stream>>>(x5, xvec, B * 512);
    // 4. head: weights + vertices
    head_kernel<<<B, 128, 0, stream>>>(xvec, wgen_w, wgen_b, ada_w, ada_b, gw, vert);
    // 5. luts
    luts_kernel<<<(LUT_CH + 255) / 256, 256, 0, stream>>>(basis_w, gw, luts, B);
    // 6. transform
    dim3 tg((2048 * 2048) / 1024, B);
    transform_kernel<<<tg, 256, 0, stream>>>(imgs, luts, vert, out);
}

// Round 2
// 487.254 us; speedup vs baseline: 1.9518x; 1.9518x over previous
//
#include <hip/hip_runtime.h>
#include <hip/hip_fp16.h>
#include <cstdint>
#include <cstddef>

#define VCUBE 35937      // 33^3
#define LUT_CH 107811    // 3*33^3

// ================= conv1: fused resize(2048->256) + conv3x3s2 + lrelu =================
// block: (b, oh, ow_tile of 16); threads 256 = 16 co x 16 ow
__global__ __launch_bounds__(256) void conv1_fused(const float* __restrict__ imgs,
    const float* __restrict__ w, const float* __restrict__ bias,
    float* __restrict__ out) {
  __shared__ float s_in[3*3*34];
  __shared__ float s_w[16*3*9];
  int bid = blockIdx.x;
  int owt = bid & 7; int oh = (bid >> 3) & 127; int b = bid >> 10;
  int t = threadIdx.x;
  int ow0 = owt * 16;
  int iwbase = 2*ow0 - 1;
  int ihbase = 2*oh - 1;
  for (int i = t; i < 3*3*34; i += 256) {
    int x = i % 34; int rest = i / 34; int kh = rest % 3; int ci = rest / 3;
    int ih = ihbase + kh;          // resized-image row
    int iw = iwbase + x;           // resized-image col
    float v = 0.f;
    if (ih >= 0 && ih < 256 && iw >= 0 && iw < 256) {
      const float* p = imgs + (size_t)(b*3+ci) * 2048 * 2048;
      int y0 = ih*8 + 3, x0 = iw*8 + 3;     // scale-8 bilinear: frac is exactly 0.5
      const float* r0 = p + (size_t)y0*2048 + x0;
      const float* r1 = r0 + 2048;
      float a = r0[0], bb = r0[1], c = r1[0], d = r1[1];
      float top = a + 0.5f*(bb - a);
      float bot = c + 0.5f*(d - c);
      v = top + 0.5f*(bot - top);
    }
    s_in[i] = v;
  }
  for (int i = t; i < 16*3*9; i += 256) s_w[i] = w[i];
  __syncthreads();
  int owl = t & 15; int co = t >> 4;
  float acc = bias[co];
  const float* wp = s_w + co*27;
#pragma unroll
  for (int ci = 0; ci < 3; ci++) {
#pragma unroll
    for (int kh = 0; kh < 3; kh++) {
      const float* rp = s_in + (ci*3 + kh)*34 + 2*owl;
      acc = fmaf(rp[0], wp[ci*9 + kh*3 + 0], acc);
      acc = fmaf(rp[1], wp[ci*9 + kh*3 + 1], acc);
      acc = fmaf(rp[2], wp[ci*9 + kh*3 + 2], acc);
    }
  }
  acc = acc >= 0.f ? acc : 0.2f*acc;
  out[(((size_t)b*16 + co)*128 + oh)*128 + ow0 + owl] = acc;
}

// ================= generic conv3x3 s2 pad1 + lrelu, LDS row tiling =================
// block: (b, oh, co_group); threads 256 = COPB x OS
template<int CI, int CO, int IS, int COPB, bool WLDS>
__global__ __launch_bounds__(256) void conv_row(const float* __restrict__ in,
    const float* __restrict__ w, const float* __restrict__ bias,
    float* __restrict__ out) {
  constexpr int OS = IS/2;
  constexpr int PW = IS + 2;
  constexpr int NG = CO/COPB;
  constexpr int E  = CI*3*PW;
  static_assert(COPB*OS == 256, "block mismatch");
  __shared__ float s_in[E];
  __shared__ float s_w[WLDS ? COPB*CI*9 : 1];
  int bid = blockIdx.x;
  int grp = bid % NG; int rest = bid / NG; int oh = rest % OS; int b = rest / OS;
  int t = threadIdx.x;
  int ihb = 2*oh - 1;
  for (int i = t; i < E; i += 256) {
    int x = i % PW; int r2 = i / PW; int kh = r2 % 3; int ci = r2 / 3;
    int ih = ihb + kh; int iw = x - 1;
    float v = 0.f;
    if (ih >= 0 && ih < IS && iw >= 0 && iw < IS)
      v = in[((size_t)(b*CI + ci)*IS + ih)*IS + iw];
    s_in[i] = v;
  }
  if (WLDS) {
    const float* wg = w + (size_t)grp*COPB*CI*9;
    for (int i = t; i < COPB*CI*9; i += 256) s_w[i] = wg[i];
  }
  __syncthreads();
  int ow = t % OS; int col = t / OS;
  int co = grp*COPB + col;
  float acc = bias[co];
  const float* wp = WLDS ? (s_w + col*CI*9) : (w + (size_t)co*CI*9);
  for (int ci = 0; ci < CI; ci++) {
    const float* rowp = s_in + ci*3*PW;
    const float* wc = wp + ci*9;
#pragma unroll
    for (int kh = 0; kh < 3; kh++) {
      const float* rp = rowp + kh*PW + 2*ow;
      acc = fmaf(rp[0], wc[kh*3 + 0], acc);
      acc = fmaf(rp[1], wc[kh*3 + 1], acc);
      acc = fmaf(rp[2], wc[kh*3 + 2], acc);
    }
  }
  acc = acc >= 0.f ? acc : 0.2f*acc;
  out[(((size_t)b*CO + co)*OS + oh)*OS + ow] = acc;
}

// ================= instance norm (in place), one block per (b,c) =================
__global__ __launch_bounds__(256) void inorm_kernel(float* __restrict__ x,
    const float* __restrict__ g, const float* __restrict__ be, int C, int HW) {
  int plane = blockIdx.x;
  int c = plane % C;
  float* p = x + (size_t)plane * HW;
  int t = threadIdx.x;
  float s = 0.f, s2 = 0.f;
  for (int i = t; i < HW; i += 256) {
    float v = p[i];
    s += v;
    s2 = fmaf(v, v, s2);
  }
  __shared__ float ss[256], sq[256];
  ss[t] = s; sq[t] = s2;
  __syncthreads();
  for (int off = 128; off > 0; off >>= 1) {
    if (t < off) { ss[t] += ss[t + off]; sq[t] += sq[t + off]; }
    __syncthreads();
  }
  __shared__ float sc, sh;
  if (t == 0) {
    float inv_n = 1.0f / (float)HW;
    float mean = ss[0] * inv_n;
    float var  = sq[0] * inv_n - mean*mean;
    float scale = g[c] / sqrtf(var + 1e-5f);
    sc = scale;
    sh = be[c] - mean*scale;
  }
  __syncthreads();
  for (int i = t; i < HW; i += 256) p[i] = fmaf(p[i], sc, sh);
}

// ================= head: pool + gemvs + softmax/cumsum + hint/inv tables =================
__global__ __launch_bounds__(128) void head_kernel(const float* __restrict__ x5,
    const float* __restrict__ wgen_w, const float* __restrict__ wgen_b,
    const float* __restrict__ ada_w, const float* __restrict__ ada_b,
    float* __restrict__ gweights, float* __restrict__ vertices,
    float* __restrict__ invtab, uint8_t* __restrict__ hints) {
  int b = blockIdx.x; int t = threadIdx.x;
  __shared__ float xv[512];
  __shared__ float logits[96];
  __shared__ float svp[99];
  // 4x4 avg pool (128,8,8) -> 512
  for (int o = t; o < 512; o += 128) {
    int c = o >> 2; int h2 = (o >> 1) & 1; int w2 = o & 1;
    const float* p = x5 + ((size_t)(b*128 + c))*64 + h2*32 + w2*4;
    float s = 0.f;
#pragma unroll
    for (int h = 0; h < 4; h++)
#pragma unroll
      for (int ww = 0; ww < 4; ww++) s += p[h*8 + ww];
    xv[o] = s * (1.f/16.f);
  }
  __syncthreads();
  if (t < 96) {
    float s = ada_b[t];
    for (int k = 0; k < 512; k++) s = fmaf(xv[k], ada_w[k*96 + t], s);
    logits[t] = s;
  } else if (t < 99) {
    int j = t - 96;
    float s = wgen_b[j];
    for (int k = 0; k < 512; k++) s = fmaf(xv[k], wgen_w[k*3 + j], s);
    gweights[b*3 + j] = s;
  }
  __syncthreads();
  if (t < 3) {
    const float* l = logits + t*32;
    float m = l[0];
#pragma unroll
    for (int i = 1; i < 32; i++) m = fmaxf(m, l[i]);
    float e[32]; float sum = 0.f;
#pragma unroll
    for (int i = 0; i < 32; i++) { e[i] = expf(l[i] - m); sum += e[i]; }
    float inv = 1.0f / sum;
    float* vp = vertices + b*99 + t*33;
    svp[t*33] = 0.f; vp[0] = 0.f;
    float cum = 0.f;
#pragma unroll
    for (int i = 0; i < 32; i++) { cum = fmaf(e[i], inv, cum); svp[t*33 + i + 1] = cum; vp[i + 1] = cum; }
  }
  __syncthreads();
  if (t < 96) {
    int c = t >> 5, i = t & 31;
    float d = svp[c*33 + i + 1] - svp[c*33 + i];
    invtab[b*96 + t] = 1.0f / fmaxf(d, 1e-10f);
  }
  // 1024-bin hint per channel: searchsorted_right(v, bin/1024)-1 clipped to [0,31]
  for (int e = t; e < 3072; e += 128) {
    int c = e >> 10; int bin = e & 1023;
    float q0 = (float)bin * (1.f/1024.f);
    const float* v = svp + c*33;
    int lo = 0, hi = 33;
    while (lo < hi) { int mid = (lo + hi) >> 1; if (v[mid] <= q0) lo = mid + 1; else hi = mid; }
    int idx = lo - 1; if (idx > 31) idx = 31;
    hints[b*3072 + e] = (uint8_t)idx;
  }
}

// ================= packed fp16 cell table: (bl,g,r) in 32^3, 24 vals + pad = 64B =================
__global__ __launch_bounds__(256) void ecell_build(const float* __restrict__ basis_w,
    const float* __restrict__ gw, __half* __restrict__ ecell, int B) {
  int tid = blockIdx.x*256 + threadIdx.x;
  int total = B * 32768 * 3;
  if (tid >= total) return;
  int cc = tid % 3;
  int cell = tid / 3;
  int r = cell & 31; int g = (cell >> 5) & 31; int bl = (cell >> 10) & 31; int b = cell >> 15;
  float w0 = gw[b*3 + 0], w1 = gw[b*3 + 1], w2 = gw[b*3 + 2];
  union { __half h[8]; uint4 u; } pk;
#pragma unroll
  for (int dbl = 0; dbl < 2; dbl++)
#pragma unroll
    for (int dg = 0; dg < 2; dg++)
#pragma unroll
      for (int dr = 0; dr < 2; dr++) {
        int flat = cc*VCUBE + ((bl + dbl)*33 + (g + dg))*33 + (r + dr);
        float val = w0*basis_w[flat] + w1*basis_w[LUT_CH + flat] + w2*basis_w[2*LUT_CH + flat];
        pk.h[dbl*4 + dg*2 + dr] = __float2half(val);
      }
  *(uint4*)((uint16_t*)ecell + (size_t)cell*32 + cc*8) = pk.u;
}

// ================= transform =================
__device__ __forceinline__ void lut_px(float R, float G, float Bl,
    const __half* __restrict__ ec, const float* sv, const float* sinv,
    const uint8_t* shint, float* o0, float* o1, float* o2) {
  float q[3] = { fminf(fmaxf(R, 0.f), 1.f), fminf(fmaxf(G, 0.f), 1.f), fminf(fmaxf(Bl, 0.f), 1.f) };
  int id[3]; float fr[3];
#pragma unroll
  for (int c = 0; c < 3; c++) {
    float qc = q[c];
    int bin = (int)(qc * 1024.f); bin = bin > 1023 ? 1023 : bin;
    int idx = shint[(c << 10) + bin];
    const float* v = sv + c*33;
#pragma unroll
    for (int it = 0; it < 3; it++)
      idx += (idx < 31 && v[idx + 1] <= qc) ? 1 : 0;
    float f = (qc - v[idx]) * sinv[(c << 5) + idx];
    fr[c] = fminf(fmaxf(f, 0.f), 1.f);
    id[c] = idx;
  }
  const __half* cell = ec + ((size_t)(((id[2] << 5) + id[1]) << 5) + id[0]) * 32;
  float fR = fr[0], fG = fr[1], fB = fr[2];
  float res[3];
#pragma unroll
  for (int cc = 0; cc < 3; cc++) {
    uint4 u = *(const uint4*)(cell + cc*8);
    const __half* h = (const __half*)&u;
    float f0 = __half2float(h[0]), f1 = __half2float(h[1]);
    float f2 = __half2float(h[2]), f3 = __half2float(h[3]);
    float f4 = __half2float(h[4]), f5 = __half2float(h[5]);
    float f6 = __half2float(h[6]), f7 = __half2float(h[7]);
    float l00 = fmaf(fR, f1 - f0, f0);
    float l01 = fmaf(fR, f3 - f2, f2);
    float L0  = fmaf(fG, l01 - l00, l00);
    float l10 = fmaf(fR, f5 - f4, f4);
    float l11 = fmaf(fR, f7 - f6, f6);
    float L1  = fmaf(fG, l11 - l10, l10);
    res[cc] = fmaf(fB, L1 - L0, L0);
  }
  *o0 = res[0]; *o1 = res[1]; *o2 = res[2];
}

__global__ __launch_bounds__(256) void transform_kernel(const float* __restrict__ imgs,
    const __half* __restrict__ ecell, const float* __restrict__ vert,
    const float* __restrict__ invtab, const unsigned int* __restrict__ hintw,
    float* __restrict__ out, int B) {
  const size_t N = 2048u*2048u;
  __shared__ float sv[99];
  __shared__ float sinv[96];
  __shared__ unsigned int shint_w[768];
  int b = blockIdx.x % B;          // XCD parity split for B=2 (round-robin block->XCD)
  int pblk = blockIdx.x / B;
  int t = threadIdx.x;
  if (t < 99) sv[t] = vert[b*99 + t];
  if (t < 96) sinv[t] = invtab[b*96 + t];
  for (int i = t; i < 768; i += 256) shint_w[i] = hintw[b*768 + i];
  __syncthreads();
  const uint8_t* shint = (const uint8_t*)shint_w;
  size_t pix = ((size_t)pblk*256 + t) * 4;
  const float* ip = imgs + (size_t)b*3*N;
  float* op = out + (size_t)b*3*N;
  const __half* ec = ecell + (size_t)b*1048576;
  float4 r  = *(const float4*)(ip + pix);
  float4 g  = *(const float4*)(ip + N + pix);
  float4 bb = *(const float4*)(ip + 2*N + pix);
  float4 o0, o1, o2;
  lut_px(r.x, g.x, bb.x, ec, sv, sinv, shint, &o0.x, &o1.x, &o2.x);
  lut_px(r.y, g.y, bb.y, ec, sv, sinv, shint, &o0.y, &o1.y, &o2.y);
  lut_px(r.z, g.z, bb.z, ec, sv, sinv, shint, &o0.z, &o1.z, &o2.z);
  lut_px(r.w, g.w, bb.w, ec, sv, sinv, shint, &o0.w, &o1.w, &o2.w);
  *(float4*)(op + pix) = o0;
  *(float4*)(op + N + pix) = o1;
  *(float4*)(op + 2*N + pix) = o2;
}

// ================= launch =================
extern "C" void kernel_launch(void* const* d_in, const int* in_sizes, int n_in,
                              void* d_out, int out_size, void* d_ws, size_t ws_size,
                              hipStream_t stream) {
  const float* imgs = (const float*)d_in[0];
  const float* w1 = (const float*)d_in[1];  const float* b1 = (const float*)d_in[2];
  const float* g1 = (const float*)d_in[3];  const float* be1 = (const float*)d_in[4];
  const float* w2 = (const float*)d_in[5];  const float* b2 = (const float*)d_in[6];
  const float* g2 = (const float*)d_in[7];  const float* be2 = (const float*)d_in[8];
  const float* w3 = (const float*)d_in[9];  const float* b3 = (const float*)d_in[10];
  const float* g3 = (const float*)d_in[11]; const float* be3 = (const float*)d_in[12];
  const float* w4 = (const float*)d_in[13]; const float* b4 = (const float*)d_in[14];
  const float* g4 = (const float*)d_in[15]; const float* be4 = (const float*)d_in[16];
  const float* w5 = (const float*)d_in[17]; const float* b5 = (const float*)d_in[18];
  const float* wgen_w  = (const float*)d_in[19];
  const float* wgen_b  = (const float*)d_in[20];
  const float* basis_w = (const float*)d_in[21];
  const float* ada_w   = (const float*)d_in[22];
  const float* ada_b   = (const float*)d_in[23];
  float* out = (float*)d_out;

  const int B = in_sizes[0] / (3*2048*2048);

  // workspace: region A (x1..x5 stack, later overwritten by ecell) + small tail
  char* wsb = (char*)d_ws;
  __half* ecell = (__half*)wsb;                 // B * 2,097,152 bytes (32768 cells * 64B)
  size_t A_bytes = (size_t)B * 2097152;
  float* x1 = (float*)wsb;                      // B*262144
  float* x2 = x1 + (size_t)B*262144;            // B*131072
  float* x3 = x2 + (size_t)B*131072;            // B*65536
  float* x4 = x3 + (size_t)B*65536;             // B*32768
  float* x5 = x4 + (size_t)B*32768;             // B*8192  (ends < A_bytes)
  float* tail = (float*)(wsb + A_bytes);
  float* gw   = tail;                           // B*3 (pad 4)
  float* vert = gw + (size_t)B*4;               // B*99
  float* invt = vert + (size_t)B*99;            // B*96
  uint8_t* hints = (uint8_t*)(invt + (size_t)B*96);  // B*3072 bytes

  conv1_fused<<<B*1024, 256, 0, stream>>>(imgs, w1, b1, x1);
  inorm_kernel<<<B*16, 256, 0, stream>>>(x1, g1, be1, 16, 128*128);
  conv_row<16, 32, 128, 4, true><<<B*512, 256, 0, stream>>>(x1, w2, b2, x2);
  inorm_kernel<<<B*32, 256, 0, stream>>>(x2, g2, be2, 32, 64*64);
  conv_row<32, 64, 64, 8, true><<<B*256, 256, 0, stream>>>(x2, w3, b3, x3);
  inorm_kernel<<<B*64, 256, 0, stream>>>(x3, g3, be3, 64, 32*32);
  conv_row<64, 128, 32, 16, true><<<B*128, 256, 0, stream>>>(x3, w4, b4, x4);
  inorm_kernel<<<B*128, 256, 0, stream>>>(x4, g4, be4, 128, 16*16);
  conv_row<128, 128, 16, 32, false><<<B*32, 256, 0, stream>>>(x4, w5, b5, x5);
  head_kernel<<<B, 128, 0, stream>>>(x5, wgen_w, wgen_b, ada_w, ada_b, gw, vert, invt, hints);
  ecell_build<<<B*384, 256, 0, stream>>>(basis_w, gw, ecell, B);
  transform_kernel<<<B*4096, 256, 0, stream>>>(imgs, ecell, vert, invt,
                                               (const unsigned int*)hints, out, B);
}